// Round 5
// baseline (395.954 us; speedup 1.0000x reference)
//
#include <hip/hip_runtime.h>
#include <hip/hip_bf16.h>
#include <stdint.h>
#include <math.h>

typedef __attribute__((ext_vector_type(8))) short bf16x8;
typedef __attribute__((ext_vector_type(4))) float f32x4;

#define D_K 256

__device__ __forceinline__ unsigned short f2bf(float f) {
    unsigned u = __float_as_uint(f);
    u += 0x7fffu + ((u >> 16) & 1u);   // round-to-nearest-even
    return (unsigned short)(u >> 16);
}
__device__ __forceinline__ float bf2f(unsigned short u) {
    return __uint_as_float(((unsigned)u) << 16);
}
__device__ __forceinline__ void gload_lds16(const void* g, void* l) {
    __builtin_amdgcn_global_load_lds(
        (const __attribute__((address_space(1))) void*)g,
        (__attribute__((address_space(3))) void*)l,
        16, 0, 0);
}

// ---------------- Kernel 1: row-normalize z -> bf16; zero partials ----------------
__global__ void normalize_k(const float* __restrict__ z,
                            unsigned short* __restrict__ zn,
                            float* __restrict__ part, int N) {
    int gid  = blockIdx.x * blockDim.x + threadIdx.x;
    if (gid < 5 * N) part[gid] = 0.f;
    int gw   = gid >> 6;
    int lane = threadIdx.x & 63;
    if (gw >= N) return;
    float4 v = reinterpret_cast<const float4*>(z + (size_t)gw * D_K)[lane];
    float ss = v.x * v.x + v.y * v.y + v.z * v.z + v.w * v.w;
#pragma unroll
    for (int m = 32; m; m >>= 1) ss += __shfl_xor(ss, m);
    float sc = 1.0f / fmaxf(sqrtf(ss), 1e-8f);
    ushort4 o;
    o.x = f2bf(v.x * sc); o.y = f2bf(v.y * sc);
    o.z = f2bf(v.z * sc); o.w = f2bf(v.w * sc);
    reinterpret_cast<ushort4*>(zn + (size_t)gw * D_K)[lane] = o;
}

// ---------------- Kernel 2: transpose zn [N][256] -> znT [256][N] ----------------
__global__ void transpose_k(const unsigned short* __restrict__ zn,
                            unsigned short* __restrict__ znT, int N) {
    __shared__ unsigned short T[64][72];   // pad 72: 144B rows, 8B-aligned ushort4 slots
    int njb = N >> 6;
    int jb = blockIdx.x % njb;
    int db = blockIdx.x / njb;             // 0..3
    int tid = threadIdx.x;
    int r  = tid >> 2;                     // 0..63
    int c0 = (tid & 3) << 4;               // 0,16,32,48
    const ushort4* src = reinterpret_cast<const ushort4*>(
        zn + (size_t)(jb * 64 + r) * D_K + db * 64 + c0);
#pragma unroll
    for (int k = 0; k < 4; ++k)
        *reinterpret_cast<ushort4*>(&T[r][c0 + k * 4]) = src[k];
    __syncthreads();
    int dr = tid >> 2;                     // d within tile
    int j0 = (tid & 3) << 4;
    ushort4* dst = reinterpret_cast<ushort4*>(
        znT + (size_t)(db * 64 + dr) * N + jb * 64 + j0);
#pragma unroll
    for (int k = 0; k < 4; ++k) {
        ushort4 o;
        o.x = T[j0 + k * 4 + 0][dr];
        o.y = T[j0 + k * 4 + 1][dr];
        o.z = T[j0 + k * 4 + 2][dr];
        o.w = T[j0 + k * 4 + 3][dr];
        dst[k] = o;
    }
}

// Stage znT tile [256 d][32 j] bf16 = 16 KB into LDS (linear [d][64B-row]).
__device__ __forceinline__ void stage_znT(char* dst, const unsigned short* znT,
                                          int j0, int N, int tid, int wid) {
#pragma unroll
    for (int r = 0; r < 4; ++r) {
        int l = r * 4096 + tid * 16;
        int d = l >> 6;
        int c = l & 63;
        const char* src = reinterpret_cast<const char*>(znT) +
                          (size_t)d * (N * 2) + (size_t)j0 * 2 + c;
        gload_lds16(src, dst + r * 4096 + wid * 1024);
    }
}

// Stage zn j-tile [32 rows][256 d] bf16 = 16 KB, XOR-swizzled via source.
__device__ __forceinline__ void stage_zn(char* dst, const unsigned short* zn,
                                         int j0, int tid, int wid) {
#pragma unroll
    for (int r = 0; r < 4; ++r) {
        int l   = r * 4096 + tid * 16;
        int row = l >> 9;
        int c   = l & 511;
        const char* src = reinterpret_cast<const char*>(zn) +
                          ((size_t)(j0 + row) << 9) + (size_t)(c ^ ((row & 7) << 4));
        gload_lds16(src, dst + r * 4096 + wid * 1024);
    }
}

// ---------------- Kernel 3: merged stream-GEMM + den pass ----------------
// even blocks (1024): stream path — G_part = X@zn over k-chunk; S1_i = zn_i.G_i/T,
//   rowsum_i accumulated in-flight. Pre-MFMA operand streaming, counted vmcnt.
// odd blocks (1024): den path — den_i = sum_{j!=i} exp(zn_i.zn_j/T), L2-only.
// part: [0,N) den | [N,2N) S1 | [2N,3N) A | [3N,4N) T1 | [4N,5N) T
__global__ __launch_bounds__(256, 4) void main_k(
    const unsigned short* __restrict__ zn,
    const unsigned short* __restrict__ znT,
    const float* __restrict__ adj,
    const float* __restrict__ tsim,
    float* __restrict__ part, int N) {
    __shared__ alignas(128) char L[2][16384];

    const float INV_T = 1.0f / 0.07f;
    int bid = blockIdx.x;
    int tid = threadIdx.x;
    int wid = tid >> 6, lane = tid & 63;
    int l15 = lane & 15, lhi = lane >> 4;
    int NIB = N >> 6;

    if ((bid & 1) == 0) {
        // ================= STREAM PATH =================
        int s   = bid >> 1;            // 0..1023
        int arr = s & 1;
        int t2  = s >> 1;              // 0..511
        int ib  = t2 & (NIB - 1);
        int kc  = t2 >> 7;             // 0..3
        const float* X = arr ? tsim : adj;
        float* s1dst = part + (size_t)(arr ? 3 : 1) * N;
        float* rsdst = part + (size_t)(arr ? 4 : 2) * N;
        int i0w = ib * 64 + wid * 16;
        int k0  = kc * (N >> 2);
        const int NKS = N >> 7;        // 64 ksteps of 32

        const float* arow = X + (size_t)(i0w + l15) * N + k0 + lhi * 8;

        f32x4 acc[16];
#pragma unroll
        for (int t = 0; t < 16; ++t) acc[t] = (f32x4){0.f, 0.f, 0.f, 0.f};

        // prologue: stage tile 0, load A(0)   (outstanding: stage x4, A x2)
        stage_znT(L[0], znT, k0, N, tid, wid);
        f32x4 a0 = __builtin_nontemporal_load(reinterpret_cast<const f32x4*>(arow));
        f32x4 a1 = __builtin_nontemporal_load(reinterpret_cast<const f32x4*>(arow + 4));
        float rs = 0.f;
        int cur = 0;

        for (int ks = 0; ks < NKS; ++ks) {
            // own staging (4 oldest) complete; A-prefetch (2 newest) may stay in flight
            asm volatile("s_waitcnt vmcnt(2)" ::: "memory");
            __builtin_amdgcn_s_barrier();
            __builtin_amdgcn_sched_barrier(0);

            if (ks + 1 < NKS)
                stage_znT(L[cur ^ 1], znT, k0 + (ks + 1) * 32, N, tid, wid);
            f32x4 na0 = a0, na1 = a1;
            if (ks + 1 < NKS) {
                const float* nr = arow + (size_t)(ks + 1) * 32;
                na0 = __builtin_nontemporal_load(reinterpret_cast<const f32x4*>(nr));
                na1 = __builtin_nontemporal_load(reinterpret_cast<const f32x4*>(nr + 4));
            }

            // rowsum (exact f32) + cvt to bf16 A-fragment
            bf16x8 ab;
#pragma unroll
            for (int e = 0; e < 4; ++e) { rs += a0[e]; ab[e]     = (short)f2bf(a0[e]); }
#pragma unroll
            for (int e = 0; e < 4; ++e) { rs += a1[e]; ab[4 + e] = (short)f2bf(a1[e]); }

            const char* bb = L[cur];
#pragma unroll
            for (int t = 0; t < 16; ++t) {
                bf16x8 bf = *reinterpret_cast<const bf16x8*>(bb + (t * 16 + l15) * 64 + lhi * 16);
                acc[t] = __builtin_amdgcn_mfma_f32_16x16x32_bf16(ab, bf, acc[t], 0, 0, 0);
            }
            a0 = na0; a1 = na1;
            cur ^= 1;
        }

        // dot epilogue: lane holds G[i0w + lhi*4 + rr][t*16 + l15]
        float dsum[4] = {0.f, 0.f, 0.f, 0.f};
        const unsigned short* zr = zn + (size_t)(i0w + lhi * 4) * D_K + l15;
#pragma unroll
        for (int t = 0; t < 16; ++t) {
#pragma unroll
            for (int rr = 0; rr < 4; ++rr)
                dsum[rr] = fmaf(bf2f(zr[rr * D_K + t * 16]), acc[t][rr], dsum[rr]);
        }
#pragma unroll
        for (int rr = 0; rr < 4; ++rr) {
            float v = dsum[rr];
            v += __shfl_xor(v, 1); v += __shfl_xor(v, 2);
            v += __shfl_xor(v, 4); v += __shfl_xor(v, 8);
            if (l15 == 0) atomicAdd(s1dst + i0w + lhi * 4 + rr, v * INV_T);
        }
        rs += __shfl_xor(rs, 16); rs += __shfl_xor(rs, 32);
        if (lhi == 0) atomicAdd(rsdst + i0w + l15, rs);
    } else {
        // ================= DEN PATH =================
        int d  = bid >> 1;             // 0..1023
        int ib = d & (NIB - 1);
        int jc = d >> 7;               // 0..7
        int gi = ib * 64 + wid * 16 + l15;
        int jbase = jc * (N >> 3);
        const int NT = N >> 8;         // 32 tiles of 32 j

        bf16x8 bfr[8];
        {
            const bf16x8* bp = reinterpret_cast<const bf16x8*>(zn + (size_t)gi * D_K) + lhi;
#pragma unroll
            for (int ks = 0; ks < 8; ++ks) bfr[ks] = bp[ks * 4];
        }
        float accden = 0.f;

        stage_zn(L[0], zn, jbase, tid, wid);
        __syncthreads();

        for (int jt = 0; jt < NT; ++jt) {
            if (jt + 1 < NT)
                stage_zn(L[(jt & 1) ^ 1], zn, jbase + (jt + 1) * 32, tid, wid);
            const char* buf = L[jt & 1];
            f32x4 acc2[2] = {(f32x4){0.f,0.f,0.f,0.f}, (f32x4){0.f,0.f,0.f,0.f}};
#pragma unroll
            for (int ks = 0; ks < 8; ++ks) {
#pragma unroll
                for (int t = 0; t < 2; ++t) {
                    int brow = t * 16 + l15;
                    int boff = (brow << 9) + (((ks << 6) + (lhi << 4)) ^ ((brow & 7) << 4));
                    bf16x8 aj = *reinterpret_cast<const bf16x8*>(buf + boff);
                    acc2[t] = __builtin_amdgcn_mfma_f32_16x16x32_bf16(aj, bfr[ks], acc2[t], 0, 0, 0);
                }
            }
            int j0 = jbase + jt * 32;
#pragma unroll
            for (int t = 0; t < 2; ++t) {
                int gj0 = j0 + t * 16 + lhi * 4;
#pragma unroll
                for (int r = 0; r < 4; ++r) {
                    float sim = acc2[t][r] * INV_T;
                    accden += (gi == gj0 + r) ? 0.f : __expf(sim);
                }
            }
            __syncthreads();
        }
        accden += __shfl_xor(accden, 16); accden += __shfl_xor(accden, 32);
        if (lhi == 0) atomicAdd(part + gi, accden);
    }
}

// ---------------- Kernel 4: finalize scalar ----------------
__global__ void finalize_k(const float* __restrict__ part, float* __restrict__ out, int N) {
    const float* den = part;
    const float* s1  = part + (size_t)N;
    const float* aa  = part + (size_t)2 * N;
    const float* t1  = part + (size_t)3 * N;
    const float* tt  = part + (size_t)4 * N;
    float acc = 0.f;
    for (int i = threadIdx.x; i < N; i += blockDim.x) {
        float ld = logf(den[i] + 1e-8f);
        acc += -(s1[i] - ld * aa[i]) / (aa[i] + 1e-8f)
               - (t1[i] - ld * tt[i]) / (tt[i] + 1e-8f);
    }
#pragma unroll
    for (int m = 32; m; m >>= 1) acc += __shfl_xor(acc, m);
    __shared__ float red[16];
    if ((threadIdx.x & 63) == 0) red[threadIdx.x >> 6] = acc;
    __syncthreads();
    if (threadIdx.x == 0) {
        float tot = 0.f;
        int nw = blockDim.x >> 6;
        for (int w = 0; w < nw; ++w) tot += red[w];
        out[0] = tot / (float)N;
    }
}

extern "C" void kernel_launch(void* const* d_in, const int* in_sizes, int n_in,
                              void* d_out, int out_size, void* d_ws, size_t ws_size,
                              hipStream_t stream) {
    const float* z    = (const float*)d_in[0];
    const float* adj  = (const float*)d_in[1];
    const float* tsim = (const float*)d_in[2];

    int N = (int)(sqrt((double)in_sizes[1]) + 0.5);  // 8192

    unsigned short* zn  = (unsigned short*)d_ws;                           // 4 MB
    unsigned short* znT = (unsigned short*)((char*)d_ws + (size_t)N * D_K * 2);  // 4 MB
    float* part = (float*)((char*)d_ws + (size_t)2 * N * D_K * 2);         // 5*N f32

    normalize_k<<<N / 4, 256, 0, stream>>>(z, zn, part, N);
    transpose_k<<<(N >> 6) * (D_K >> 6), 256, 0, stream>>>(zn, znT, N);
    main_k<<<2048, 256, 0, stream>>>(zn, znT, adj, tsim, part, N);
    finalize_k<<<1, 1024, 0, stream>>>(part, (float*)d_out, N);
}

// Round 6
// 186.398 us; speedup vs baseline: 2.1242x; 2.1242x over previous
//
#include <hip/hip_runtime.h>
#include <hip/hip_bf16.h>
#include <stdint.h>
#include <math.h>

typedef __attribute__((ext_vector_type(8))) short bf16x8;
typedef __attribute__((ext_vector_type(4))) float f32x4;

#define D_K 256
#define JCHUNK 1024
#define BN 32
#define NT (JCHUNK / BN)    // 32 tiles per block

__device__ __forceinline__ unsigned short f2bf(float f) {
    unsigned u = __float_as_uint(f);
    u += 0x7fffu + ((u >> 16) & 1u);   // round-to-nearest-even
    return (unsigned short)(u >> 16);
}

__device__ __forceinline__ void gload_lds16(const void* g, void* l) {
    __builtin_amdgcn_global_load_lds(
        (const __attribute__((address_space(1))) void*)g,
        (__attribute__((address_space(3))) void*)l,
        16, 0, 0);
}

// ---------------- Kernel 1: row-normalize z -> bf16; zero partials ----------------
__global__ void normalize_k(const float* __restrict__ z,
                            unsigned short* __restrict__ zn,
                            float* __restrict__ part, int N) {
    int gid  = blockIdx.x * blockDim.x + threadIdx.x;
    if (gid < 5 * N) part[gid] = 0.f;      // stream-ordered before fused_k
    int gw   = gid >> 6;                   // one wave per row
    int lane = threadIdx.x & 63;
    if (gw >= N) return;
    float4 v = reinterpret_cast<const float4*>(z + (size_t)gw * D_K)[lane];
    float ss = v.x * v.x + v.y * v.y + v.z * v.z + v.w * v.w;
#pragma unroll
    for (int m = 32; m; m >>= 1) ss += __shfl_xor(ss, m);
    float sc = 1.0f / fmaxf(sqrtf(ss), 1e-8f);
    ushort4 o;
    o.x = f2bf(v.x * sc); o.y = f2bf(v.y * sc);
    o.z = f2bf(v.z * sc); o.w = f2bf(v.w * sc);
    reinterpret_cast<ushort4*>(zn + (size_t)gw * D_K)[lane] = o;
}

// Stage one 32-row x 256-d bf16 zn tile (16 KB) into LDS in [kslot][row][16B]
// layout: LDS linear li = (kslot*32 + row)*16, kslot = d-chunk of 8 bf16.
// gload_lds dest stays linear (wave-uniform base + lane*16); the layout remap
// happens on the GLOBAL source address per lane.
__device__ __forceinline__ void stage_zn(char* dst, const unsigned short* zn,
                                         int j0, int tid, int wid) {
#pragma unroll
    for (int it = 0; it < 4; ++it) {
        int li    = it * 4096 + tid * 16;
        int kslot = li >> 9;          // 0..31
        int row   = (li >> 4) & 31;   // 0..31
        const char* src = reinterpret_cast<const char*>(zn) +
                          ((size_t)(j0 + row) << 9) + (size_t)kslot * 16;
        gload_lds16(src, dst + it * 4096 + wid * 1024);
    }
}

// ---------------- Kernel 2: fused sim-GEMM + row reductions ----------------
// Swapped operands: LDS-staged j-rows are MFMA A (output rows = j), register-held
// i-row zn_gi is B (output cols = i = lane&15). Lane owns j = j0+t*16+lhi*4+rr.
// Pipeline per tile k: [stage(k+1); stream(k+1)] -> MFMA(k) -> consume stream(k)
// -> vmcnt(4) (stage(k+1) only; stream(k+1) stays in flight) -> barrier.
// part: [0,N) den | [N,2N) S1 | [2N,3N) A | [3N,4N) T1 | [4N,5N) T
__global__ __launch_bounds__(256, 4) void fused_k(
    const unsigned short* __restrict__ zn,
    const float* __restrict__ adj,
    const float* __restrict__ tsim,
    float* __restrict__ part, int N) {
    __shared__ alignas(128) char L[2][BN * 512];   // 2 x 16 KB

    const float INV_T = 1.0f / 0.07f;
    const int NIB = N >> 6;
    int ib  = blockIdx.x & (NIB - 1);
    int jc  = blockIdx.x / NIB;
    int tid = threadIdx.x;
    int wid = tid >> 6, lane = tid & 63;
    int l15 = lane & 15, lhi = lane >> 4;
    int gi  = ib * 64 + wid * 16 + l15;     // this lane's i-row (output col)
    int jbase = jc * JCHUNK;

    // B-operand fragments: zn row gi, in registers for the whole sweep (32 VGPRs)
    bf16x8 bfr[8];
    {
        const bf16x8* bp = reinterpret_cast<const bf16x8*>(zn + (size_t)gi * D_K) + lhi;
#pragma unroll
        for (int ks = 0; ks < 8; ++ks) bfr[ks] = bp[ks * 4];
    }

    float accden = 0.f, accs1 = 0.f, acca = 0.f, acct1 = 0.f, acctt = 0.f;

    const float* abase = adj  + (size_t)gi * N + jbase + lhi * 4;
    const float* tbase = tsim + (size_t)gi * N + jbase + lhi * 4;

    // prologue: stage tile 0, then stream loads tile 0 (newer than stage)
    stage_zn(L[0], zn, jbase, tid, wid);
    f32x4 av[2], tv[2];
#pragma unroll
    for (int t = 0; t < 2; ++t) {
        av[t] = __builtin_nontemporal_load(reinterpret_cast<const f32x4*>(abase + t * 16));
        tv[t] = __builtin_nontemporal_load(reinterpret_cast<const f32x4*>(tbase + t * 16));
    }
    asm volatile("s_waitcnt vmcnt(4)" ::: "memory");   // stage(0) done; stream(0) flying
    __syncthreads();

    for (int jt = 0; jt < NT; ++jt) {
        const char* buf = L[jt & 1];

        // 1) issue next tile's staging + stream loads (overlap with compute below)
        f32x4 nav[2], ntv[2];
        if (jt + 1 < NT) {
            stage_zn(L[(jt & 1) ^ 1], zn, jbase + (jt + 1) * BN, tid, wid);
            const float* an = abase + (jt + 1) * BN;
            const float* tn = tbase + (jt + 1) * BN;
#pragma unroll
            for (int t = 0; t < 2; ++t) {
                nav[t] = __builtin_nontemporal_load(reinterpret_cast<const f32x4*>(an + t * 16));
                ntv[t] = __builtin_nontemporal_load(reinterpret_cast<const f32x4*>(tn + t * 16));
            }
        }

        // 2) MFMA tile k from LDS ([kslot][row][16B]: lanes read contiguous 16B runs)
        f32x4 acc[2] = {(f32x4){0.f,0.f,0.f,0.f}, (f32x4){0.f,0.f,0.f,0.f}};
#pragma unroll
        for (int ks = 0; ks < 8; ++ks) {
#pragma unroll
            for (int t = 0; t < 2; ++t) {
                int boff = (ks << 11) + (lhi << 9) + (t << 8) + (l15 << 4);
                bf16x8 aj = *reinterpret_cast<const bf16x8*>(buf + boff);
                acc[t] = __builtin_amdgcn_mfma_f32_16x16x32_bf16(aj, bfr[ks], acc[t], 0, 0, 0);
            }
        }

        // 3) epilogue: consume stream(k) (loaded one iteration ago)
        int j0 = jbase + jt * BN;
#pragma unroll
        for (int t = 0; t < 2; ++t) {
            int gj0 = j0 + t * 16 + lhi * 4;
#pragma unroll
            for (int r = 0; r < 4; ++r) {
                float sim = acc[t][r] * INV_T;
                float e   = (gi == gj0 + r) ? 0.f : __expf(sim);
                float a   = av[t][r];
                float w   = tv[t][r];
                accden += e;
                accs1 = fmaf(a, sim, accs1);  acca  += a;
                acct1 = fmaf(w, sim, acct1);  acctt += w;
            }
        }
#pragma unroll
        for (int t = 0; t < 2; ++t) { av[t] = nav[t]; tv[t] = ntv[t]; }

        // 4) counted wait: stage(k+1) landed; stream(k+1) stays in flight
        asm volatile("s_waitcnt vmcnt(4)" ::: "memory");
        __syncthreads();
    }

    // lanes lhi=0..3 share gi: reduce, one atomic per row per counter
    accden += __shfl_xor(accden, 16); accden += __shfl_xor(accden, 32);
    accs1  += __shfl_xor(accs1, 16);  accs1  += __shfl_xor(accs1, 32);
    acca   += __shfl_xor(acca, 16);   acca   += __shfl_xor(acca, 32);
    acct1  += __shfl_xor(acct1, 16);  acct1  += __shfl_xor(acct1, 32);
    acctt  += __shfl_xor(acctt, 16);  acctt  += __shfl_xor(acctt, 32);
    if (lhi == 0) {
        atomicAdd(part + gi, accden);
        atomicAdd(part + (size_t)N + gi, accs1);
        atomicAdd(part + (size_t)2 * N + gi, acca);
        atomicAdd(part + (size_t)3 * N + gi, acct1);
        atomicAdd(part + (size_t)4 * N + gi, acctt);
    }
}

// ---------------- Kernel 3: finalize scalar ----------------
__global__ void finalize_k(const float* __restrict__ part, float* __restrict__ out, int N) {
    const float* den = part;
    const float* s1  = part + (size_t)N;
    const float* aa  = part + (size_t)2 * N;
    const float* t1  = part + (size_t)3 * N;
    const float* tt  = part + (size_t)4 * N;
    float acc = 0.f;
    for (int i = threadIdx.x; i < N; i += blockDim.x) {
        float ld = logf(den[i] + 1e-8f);
        acc += -(s1[i] - ld * aa[i]) / (aa[i] + 1e-8f)
               - (t1[i] - ld * tt[i]) / (tt[i] + 1e-8f);
    }
#pragma unroll
    for (int m = 32; m; m >>= 1) acc += __shfl_xor(acc, m);
    __shared__ float red[16];
    if ((threadIdx.x & 63) == 0) red[threadIdx.x >> 6] = acc;
    __syncthreads();
    if (threadIdx.x == 0) {
        float tot = 0.f;
        int nw = blockDim.x >> 6;
        for (int w = 0; w < nw; ++w) tot += red[w];
        out[0] = tot / (float)N;
    }
}

extern "C" void kernel_launch(void* const* d_in, const int* in_sizes, int n_in,
                              void* d_out, int out_size, void* d_ws, size_t ws_size,
                              hipStream_t stream) {
    const float* z    = (const float*)d_in[0];
    const float* adj  = (const float*)d_in[1];
    const float* tsim = (const float*)d_in[2];

    int N = (int)(sqrt((double)in_sizes[1]) + 0.5);  // 8192

    unsigned short* zn = (unsigned short*)d_ws;                   // 4 MB
    float* part = (float*)((char*)d_ws + (size_t)N * D_K * 2);    // 5*N f32

    normalize_k<<<N / 4, 256, 0, stream>>>(z, zn, part, N);

    int nblocks = (N >> 6) * (N / JCHUNK);  // 128 * 8 = 1024
    fused_k<<<nblocks, 256, 0, stream>>>(zn, adj, tsim, part, N);

    finalize_k<<<1, 1024, 0, stream>>>(part, (float*)d_out, N);
}